// Round 1
// baseline (973.055 us; speedup 1.0000x reference)
//
#include <hip/hip_runtime.h>

// Problem constants (match reference)
#define Bb   32
#define Nn   64
#define Hh   32
#define Dd   20
#define Ee   64
#define NP1  65
#define KK   (Dd * Ee)   // 1280
#define NUM_SPATIAL 512

#define KC 64            // K-chunk staged to LDS
#define RS 65            // padded LDS row stride (floats)

// ---------------------------------------------------------------------------
// K1: C[k][g], k = d*64+e:  C = sum_h W_edge[h][e] * W3[d][h][g]
// W3[d][h][g] = edge_dis_weight[(d*32+h)*32+g]
// ---------------------------------------------------------------------------
__global__ void build_C(const float* __restrict__ W_edge,
                        const float* __restrict__ edw,
                        float* __restrict__ C) {
    int idx = blockIdx.x * 256 + threadIdx.x;   // over D*E*H = 40960
    if (idx >= Dd * Ee * Hh) return;
    int g = idx & 31;
    int e = (idx >> 5) & 63;
    int d = idx >> 11;
    float s = 0.f;
#pragma unroll
    for (int h = 0; h < Hh; ++h)
        s += W_edge[h * Ee + e] * edw[(d * Hh + h) * Hh + g];
    C[idx] = s;
}

// ---------------------------------------------------------------------------
// K2: interior output  O[b][g][1+i][1+j] = 2*ab[b][1+i][1+j]
//        + spatial_emb[spos[b][i][j]][g] + (sum_k X[b,i,j,k]*C[k,g]) / sp
// Block: 256 threads = 4 waves; owns 256 contiguous X rows (4 i-rows).
// Wave w handles g in [8w, 8w+8); lane = j (pgrp); thread tile 4 pos x 8 g.
// ---------------------------------------------------------------------------
__global__ __launch_bounds__(256) void main_kernel(
    const float* __restrict__ ab,      // [B][65][65]
    const int*   __restrict__ spos,    // [B][64][64]
    const float* __restrict__ X,       // [B][64][64][20][64]
    const float* __restrict__ C,       // [1280][32]
    const float* __restrict__ semb,    // [513][32]
    float* __restrict__ O)             // [B][32][65][65]
{
    __shared__ float Xs[256 * RS];

    const int t    = threadIdx.x;
    const int b    = blockIdx.x >> 4;         // 0..31
    const int i0   = (blockIdx.x & 15) * 4;   // 0,4,...,60
    const float* Xblk = X + (size_t)(b * Nn + i0) * Nn * KK;  // 256 rows x 1280

    const int pgrp  = t & 63;                 // = j
    const int gbase = __builtin_amdgcn_readfirstlane((t >> 6) * 8);

    float acc[4][8];
#pragma unroll
    for (int r = 0; r < 4; ++r)
#pragma unroll
        for (int c = 0; c < 8; ++c) acc[r][c] = 0.f;

    for (int kc = 0; kc < KK; kc += KC) {
        // stage 256 pos x 64 k floats (each thread: 16 float4 loads)
#pragma unroll
        for (int ii = 0; ii < 16; ++ii) {
            int f   = t + 256 * ii;           // float4 index 0..4095
            int pos = f >> 4;
            int kq  = f & 15;
            const float4 v = *(const float4*)(Xblk + (size_t)pos * KK + kc + kq * 4);
            float* w = &Xs[pos * RS + kq * 4];
            w[0] = v.x; w[1] = v.y; w[2] = v.z; w[3] = v.w;
        }
        __syncthreads();

        const float* Ck = C + (size_t)kc * Hh + gbase;  // wave-uniform
#pragma unroll 4
        for (int k = 0; k < KC; ++k) {
            float x0 = Xs[(pgrp      ) * RS + k];
            float x1 = Xs[(pgrp + 64 ) * RS + k];
            float x2 = Xs[(pgrp + 128) * RS + k];
            float x3 = Xs[(pgrp + 192) * RS + k];
#pragma unroll
            for (int c = 0; c < 8; ++c) {
                float cv = Ck[k * Hh + c];    // uniform -> s_load
                acc[0][c] += x0 * cv;
                acc[1][c] += x1 * cv;
                acc[2][c] += x2 * cv;
                acc[3][c] += x3 * cv;
            }
        }
        __syncthreads();
    }

    // epilogue
    const int j = pgrp;
#pragma unroll
    for (int r = 0; r < 4; ++r) {
        int i = i0 + r;
        int spraw = spos[(b * Nn + i) * Nn + j];
        int sp = (spraw == 0) ? 1 : spraw;
        sp = (sp > 1) ? sp - 1 : sp;
        sp = (sp > Dd) ? Dd : sp;
        float inv   = 1.f / (float)sp;
        float base2 = 2.f * ab[((size_t)b * NP1 + (1 + i)) * NP1 + (1 + j)];
#pragma unroll
        for (int c = 0; c < 8; ++c) {
            int g = gbase + c;
            float v = acc[r][c] * inv + semb[spraw * Hh + g] + base2;
            O[(((size_t)b * Hh + g) * NP1 + (1 + i)) * NP1 + (1 + j)] = v;
        }
    }
}

// ---------------------------------------------------------------------------
// K3: border — i==0 row (all j) and j==0 col (i>=1):  O = 2*ab + vd[h]
// ---------------------------------------------------------------------------
__global__ void border_kernel(const float* __restrict__ ab,
                              const float* __restrict__ vd,
                              float* __restrict__ O) {
    int idx = blockIdx.x * 256 + threadIdx.x;   // B*H*129
    if (idx >= Bb * Hh * 129) return;
    int e  = idx % 129;
    int bh = idx / 129;
    int h  = bh & 31;
    int b  = bh >> 5;
    int i, j;
    if (e < 65) { i = 0; j = e; } else { i = e - 64; j = 0; }
    float v = 2.f * ab[((size_t)b * NP1 + i) * NP1 + j] + vd[h];
    O[(((size_t)b * Hh + h) * NP1 + i) * NP1 + j] = v;
}

// ---------------------------------------------------------------------------
extern "C" void kernel_launch(void* const* d_in, const int* in_sizes, int n_in,
                              void* d_out, int out_size, void* d_ws, size_t ws_size,
                              hipStream_t stream) {
    // setup_inputs() order:
    // 0 node_features (unused), 1 attn_bias, 2 spatial_pos, 3 edge_input,
    // 4 attn_edge_type (unused), 5 W_edge, 6 spatial_emb, 7 vd_weight,
    // 8 edge_dis_weight
    const float* ab   = (const float*)d_in[1];
    const int*   spos = (const int*)  d_in[2];
    const float* X    = (const float*)d_in[3];
    const float* We   = (const float*)d_in[5];
    const float* semb = (const float*)d_in[6];
    const float* vd   = (const float*)d_in[7];
    const float* edw  = (const float*)d_in[8];
    float* O = (float*)d_out;
    float* C = (float*)d_ws;   // 40960 floats = 160 KB

    build_C<<<(Dd * Ee * Hh + 255) / 256, 256, 0, stream>>>(We, edw, C);
    main_kernel<<<Bb * 16, 256, 0, stream>>>(ab, spos, X, C, semb, O);
    border_kernel<<<(Bb * Hh * 129 + 255) / 256, 256, 0, stream>>>(ab, vd, O);
}